// Round 11
// baseline (174.405 us; speedup 1.0000x reference)
//
#include <hip/hip_runtime.h>
#include <hip/hip_fp16.h>

#define N_NODES 100000
#define N_EDGES 1600000
#define NEG_SLOPE 0.2f
#define LN_EPS 1e-5f
#define NB 782            // ceil(N_NODES / 128) buckets, bucket = dst >> 7
#define GEMM_BLOCKS 782   // ceil(N_NODES / 128)
#define BIN_BLOCKS 196    // ceil(N_EDGES / 8192)
#define BIN_EDGES 8192
#define BUCKET_CAP 4096   // padded per-bucket capacity (mean 2048, sigma 45 -> safe)

typedef _Float16 f16x8 __attribute__((ext_vector_type(8)));
typedef float f32x4 __attribute__((ext_vector_type(4)));

#define XLDS_LD 136       // fp16 row stride for x_lds (128 + 8 pad -> bank spread)

// ---------------- fused MFMA-GEMM + direct-bin mega-kernel (unchanged R9) ------
// blocks [0, GEMM_BLOCKS): h16 = fp16(x @ W) via v_mfma_f32_16x16x32_f16,
//   fused a_src(fp16)/a_dst(fp32) epilogue computed from the LDS h copy.
// blocks [GEMM_BLOCKS, +BIN_BLOCKS): two-pass LDS bin of edges into PADDED
//   per-bucket regions binned[bucket*BUCKET_CAP + ...].
__global__ __launch_bounds__(256) void gemm_bin_kernel(const float* __restrict__ x,
                                                       const float* __restrict__ W,
                                                       const float* __restrict__ att_src,
                                                       const float* __restrict__ att_dst,
                                                       const int* __restrict__ ei,
                                                       __half* __restrict__ h16,
                                                       __half* __restrict__ a_srcp,
                                                       float* __restrict__ a_dstp,
                                                       int* __restrict__ bucket_cursor,
                                                       unsigned* __restrict__ binned) {
    // union LDS: GEMM uses x_lds (34,816 B) + w_frag (32,768 B); bin uses 2 int arrays
    __shared__ __align__(16) char lds[34816 + 32768];
    const int t = threadIdx.x;

    if (blockIdx.x >= GEMM_BLOCKS) {
        // ---------------- direct-bin branch ----------------
        int* hist = reinterpret_cast<int*>(lds);
        int* cbase = reinterpret_cast<int*>(lds + 4096);
        for (int i = t; i < NB; i += 256) hist[i] = 0;
        __syncthreads();
        const int e0 = (blockIdx.x - GEMM_BLOCKS) * BIN_EDGES;
        const int4* dsts = reinterpret_cast<const int4*>(ei + N_EDGES);
        const int b4 = e0 >> 2;
        for (int i = t; i < BIN_EDGES / 4; i += 256) {
            int idx = b4 + i;
            if (idx < N_EDGES / 4) {
                int4 d = dsts[idx];
                atomicAdd(&hist[d.x >> 7], 1);
                atomicAdd(&hist[d.y >> 7], 1);
                atomicAdd(&hist[d.z >> 7], 1);
                atomicAdd(&hist[d.w >> 7], 1);
            }
        }
        __syncthreads();
        for (int i = t; i < NB; i += 256) {
            int c = hist[i];
            cbase[i] = c ? atomicAdd(&bucket_cursor[i], c) : 0;
        }
        __syncthreads();
        for (int i = t; i < NB; i += 256) hist[i] = 0;   // reuse as local cursor
        __syncthreads();
        for (int i = t; i < BIN_EDGES; i += 256) {
            int e = e0 + i;
            if (e < N_EDGES) {
                int s_ = ei[e];
                int d = ei[N_EDGES + e];
                int bk = d >> 7;
                int off = atomicAdd(&hist[bk], 1);
                binned[bk * BUCKET_CAP + cbase[bk] + off] = (unsigned)((s_ << 7) | (d & 127));
            }
        }
        return;
    }

    // ---------------- MFMA GEMM branch ----------------
    _Float16* x_lds = reinterpret_cast<_Float16*>(lds);            // [128][XLDS_LD]
    _Float16* w_frag = reinterpret_cast<_Float16*>(lds + 34816);   // [4][8][64][8]
    const int nbase = blockIdx.x * 128;
    const int w = t >> 6;      // wave 0..3
    const int l = t & 63;
    const int lr = l & 15;     // A-row / B-col / D-col within tile
    const int lg = l >> 4;     // 16-lane group 0..3

    // stage x tile fp32 -> fp16 (coalesced float4 reads, 16B LDS writes)
    for (int i = t; i < 2048; i += 256) {
        int r = i >> 4, seg = i & 15;
        int gr = nbase + r;
        gr = gr < N_NODES ? gr : N_NODES - 1;
        const float4 v0 = *reinterpret_cast<const float4*>(&x[(size_t)gr * 128 + seg * 8]);
        const float4 v1 = *reinterpret_cast<const float4*>(&x[(size_t)gr * 128 + seg * 8 + 4]);
        _Float16 hb[8] = {(_Float16)v0.x, (_Float16)v0.y, (_Float16)v0.z, (_Float16)v0.w,
                          (_Float16)v1.x, (_Float16)v1.y, (_Float16)v1.z, (_Float16)v1.w};
        *reinterpret_cast<uint4*>(&x_lds[r * XLDS_LD + seg * 8]) =
            *reinterpret_cast<const uint4*>(hb);
    }
    // stage W into B-fragment order: w_frag[((ks*8+ct)*64+lane)*8 + j]
    //   = W[ks*32 + (lane>>4)*8 + j][ct*16 + (lane&15)]   (L2-hot strided reads)
    for (int s = t; s < 2048; s += 256) {
        int ks = s >> 9, ct = (s >> 6) & 7, ln = s & 63;
        int kb = ks * 32 + (ln >> 4) * 8;
        int col = ct * 16 + (ln & 15);
        _Float16 wb[8];
#pragma unroll
        for (int j = 0; j < 8; ++j) wb[j] = (_Float16)W[(size_t)(kb + j) * 128 + col];
        *reinterpret_cast<uint4*>(&w_frag[s * 8]) = *reinterpret_cast<const uint4*>(wb);
    }
    __syncthreads();

    f32x4 acc[2][8] = {};
    const int m0 = w * 32;
#pragma unroll
    for (int ks = 0; ks < 4; ++ks) {
        f16x8 a[2], b[8];
#pragma unroll
        for (int rt = 0; rt < 2; ++rt)
            a[rt] = *reinterpret_cast<const f16x8*>(
                &x_lds[(m0 + rt * 16 + lr) * XLDS_LD + ks * 32 + lg * 8]);
#pragma unroll
        for (int ct = 0; ct < 8; ++ct)
            b[ct] = *reinterpret_cast<const f16x8*>(&w_frag[((ks * 8 + ct) * 64 + l) * 8]);
#pragma unroll
        for (int rt = 0; rt < 2; ++rt)
#pragma unroll
            for (int ct = 0; ct < 8; ++ct)
                acc[rt][ct] = __builtin_amdgcn_mfma_f32_16x16x32_f16(a[rt], b[ct],
                                                                     acc[rt][ct], 0, 0, 0);
    }
    __syncthreads();   // done reading x_lds/w_frag; reuse x_lds for h output
    // D mapping (m89-verified): D[(lane>>4)*4 + reg][lane&15] per 16x16 tile
#pragma unroll
    for (int rt = 0; rt < 2; ++rt)
#pragma unroll
        for (int ct = 0; ct < 8; ++ct)
#pragma unroll
            for (int reg = 0; reg < 4; ++reg)
                x_lds[(m0 + rt * 16 + lg * 4 + reg) * XLDS_LD + ct * 16 + lr] =
                    (_Float16)acc[rt][ct][reg];
    __syncthreads();
    // coalesced h16 store
    for (int i = t; i < 2048; i += 256) {
        int r = i >> 4, seg = i & 15;
        int gr = nbase + r;
        if (gr < N_NODES)
            *reinterpret_cast<uint4*>(&h16[(size_t)gr * 128 + seg * 8]) =
                *reinterpret_cast<const uint4*>(&x_lds[r * XLDS_LD + seg * 8]);
    }
    // a_src / a_dst epilogue from the LDS h copy
    for (int idx = t; idx < 1024; idx += 256) {
        int row = idx >> 3, hd = idx & 7;
        int gr = nbase + row;
        if (gr < N_NODES) {
            float ps = 0.f, pd = 0.f;
#pragma unroll
            for (int j = 0; j < 16; ++j) {
                const float hv = (float)x_lds[row * XLDS_LD + hd * 16 + j];
                ps = fmaf(hv, att_src[hd * 16 + j], ps);
                pd = fmaf(hv, att_dst[hd * 16 + j], pd);
            }
            a_srcp[gr * 8 + hd] = __float2half_rn(ps);
            a_dstp[gr * 8 + hd] = pd;
        }
    }
}

// ---------------- fused CSR-build + aggregate + softmax + LN -------------------
// TWO blocks per bucket; block handles 64 nodes (half = blockIdx&1).
// Prologue: stage the bucket's binned entries to LDS, 64-node deg-hist + scan,
// scatter this half's edges into an LDS-local csr. Then aggregate with the
// R5-proven depth-2 loop (best measured: 83.5 µs), edge indices from LDS.
// One 64-lane wave per node; four 16-lane quarters; lane owns 8 ch (uint4 fp16).
// h16 row stride = 256 B.
__global__ __launch_bounds__(256) void agg_fused_kernel(const unsigned* __restrict__ binned,
                                                        const int* __restrict__ bucket_cursor,
                                                        const __half* __restrict__ h16,
                                                        const __half* __restrict__ a_srcp,
                                                        const float* __restrict__ a_dstp,
                                                        const float* __restrict__ x,
                                                        const float* __restrict__ bias,
                                                        const float* __restrict__ gamma,
                                                        const float* __restrict__ beta,
                                                        float* __restrict__ out) {
    __shared__ unsigned stage[BUCKET_CAP];   // 16 KB
    __shared__ int deg[64], sc[64], cur[64];
    __shared__ int lcsr[2048];               // 8 KB; half-bucket count ~1024+-32
    const int b = blockIdx.x >> 1;
    const int half = blockIdx.x & 1;
    const int t = threadIdx.x;
    const int pbase = b * BUCKET_CAP;
    const int cnt = bucket_cursor[b];
    const int node0 = (b << 7) + half * 64;

    if (t < 64) deg[t] = 0;
    __syncthreads();
    // stage bucket + histogram of this half's 64 nodes
    for (int i = t; i < cnt; i += 256) {
        unsigned p = binned[pbase + i];
        stage[i] = p;
        int dl = p & 127;
        if ((dl >> 6) == half) atomicAdd(&deg[dl & 63], 1);
    }
    __syncthreads();
    if (t < 64) sc[t] = deg[t];
    __syncthreads();
    for (int off = 1; off < 64; off <<= 1) {
        int u = (t < 64 && t >= off) ? sc[t - off] : 0;
        __syncthreads();
        if (t < 64) sc[t] += u;
        __syncthreads();
    }
    if (t < 64) cur[t] = sc[t] - deg[t];
    __syncthreads();
    // scatter this half's entries into the LDS-local csr
    for (int i = t; i < cnt; i += 256) {
        unsigned p = stage[i];
        int dl = p & 127;
        if ((dl >> 6) == half) {
            int off = atomicAdd(&cur[dl & 63], 1);
            lcsr[off] = (int)(p >> 7);
        }
    }
    __syncthreads();

    // ---------------- aggregate 64 nodes: 4 waves x 16 nodes ----------------
    const int wave = t >> 6;
    const int lane = t & 63;
    const int q = lane >> 4;           // quarter 0..3
    const int ql = lane & 15;          // lane within quarter
    const int ch = ql * 8;             // 8 channels per lane
    const int head = ql >> 1;          // 2 lanes per head
    const char* __restrict__ hbase = reinterpret_cast<const char*>(h16);
    const unsigned chb = (unsigned)(ql * 16);

#define LOADH(dst_, sidx_) \
    dst_ = *reinterpret_cast<const uint4*>(hbase + ((unsigned)(sidx_) * 256u + chb))
#define LOADA(dst_, sidx_) dst_ = __half2float(a_srcp[(sidx_) * 8 + head])

    for (int r = 0; r < 16; ++r) {
        const int nl = wave * 16 + r;
        const int node = node0 + nl;
        if (node >= N_NODES) continue;   // no barriers below -> safe

        const float adst = a_dstp[node * 8 + head];
        const int beg = sc[nl] - deg[nl];
        const int end = sc[nl];

        float s = 0.f;
        float accv[8] = {};

        int i = beg + q;
        if (i < end) {
            const int sF = lcsr[i];
            int s1 = (i + 4 < end) ? lcsr[i + 4] : sF;
            uint4 hv;
            float as;
            LOADH(hv, sF);
            LOADA(as, sF);
            while (true) {
                const uint4 hc = hv;
                const float ac = as;
                const int sN = s1;
                const int i8 = i + 8;
                s1 = (i8 < end) ? lcsr[i8] : sF;     // index 2 iterations ahead
                LOADH(hv, sN);                        // gather 1 iteration ahead
                LOADA(as, sN);

                float e = ac + adst;
                e = fmaxf(e, NEG_SLOPE * e);
                e = fminf(e, 80.f);
                const float p = __expf(e);
                s += p;
                const __half* hh = reinterpret_cast<const __half*>(&hc);
#pragma unroll
                for (int j = 0; j < 8; ++j)
                    accv[j] = fmaf(p, __half2float(hh[j]), accv[j]);

                i += 4;
                if (i >= end) break;
            }
        }

        // combine the four quarters
        s += __shfl_xor(s, 16);
        s += __shfl_xor(s, 32);
#pragma unroll
        for (int j = 0; j < 8; ++j) {
            accv[j] += __shfl_xor(accv[j], 16);
            accv[j] += __shfl_xor(accv[j], 32);
        }

        // normalize + bias + residual
        const float rs = 1.0f / (s + 1e-16f);
        const float* xrp = x + (size_t)node * 128 + ch;
        float v[8];
#pragma unroll
        for (int j = 0; j < 8; ++j) {
            const float xr = __builtin_nontemporal_load(xrp + j);
            v[j] = accv[j] * rs + bias[ch + j] + xr;
        }

        // LayerNorm: quarters identical after combine -> reduce over 16 lanes, /128
        float sum = 0.f, sq = 0.f;
#pragma unroll
        for (int j = 0; j < 8; ++j) {
            sum += v[j];
            sq = fmaf(v[j], v[j], sq);
        }
#pragma unroll
        for (int off = 8; off > 0; off >>= 1) {
            sum += __shfl_xor(sum, off);
            sq += __shfl_xor(sq, off);
        }
        const float mu = sum * (1.0f / 128.0f);
        const float var = sq * (1.0f / 128.0f) - mu * mu;
        const float inv = rsqrtf(var + LN_EPS);
        if (q == 0) {
            float o[8];
#pragma unroll
            for (int j = 0; j < 8; ++j) {
                float tt = (v[j] - mu) * inv * gamma[ch + j] + beta[ch + j];
                o[j] = tt > 0.f ? tt : 0.f;
            }
            float* op = out + (size_t)node * 128 + ch;
#pragma unroll
            for (int j = 0; j < 8; ++j) __builtin_nontemporal_store(o[j], op + j);
        }
    }
#undef LOADH
#undef LOADA
}

extern "C" void kernel_launch(void* const* d_in, const int* in_sizes, int n_in,
                              void* d_out, int out_size, void* d_ws, size_t ws_size,
                              hipStream_t stream) {
    const float* x = (const float*)d_in[0];
    const int* ei = (const int*)d_in[1];
    const float* W = (const float*)d_in[2];
    const float* att_src = (const float*)d_in[3];
    const float* att_dst = (const float*)d_in[4];
    const float* bias = (const float*)d_in[5];
    const float* gamma = (const float*)d_in[6];
    const float* beta = (const float*)d_in[7];
    float* out = (float*)d_out;

    char* base = (char*)d_ws;
    __half* h16    = (__half*)base;                     // 25.6 MB
    __half* a_srcp = (__half*)(base + 25600000);        // 1.6 MB
    float* a_dstp  = (float*)(base + 27200000);         // 3.2 MB
    unsigned* binned = (unsigned*)(base + 30400000);    // 12.81 MB (782*4096*4)
    int* bucket_cursor = (int*)(base + 43212288);       // 3,128 B

    hipMemsetAsync(bucket_cursor, 0, NB * sizeof(int), stream);
    gemm_bin_kernel<<<GEMM_BLOCKS + BIN_BLOCKS, 256, 0, stream>>>(
        x, W, att_src, att_dst, ei, h16, a_srcp, a_dstp, bucket_cursor, binned);
    agg_fused_kernel<<<NB * 2, 256, 0, stream>>>(
        binned, bucket_cursor, h16, a_srcp, a_dstp, x, bias, gamma, beta, out);
}

// Round 12
// 147.461 us; speedup vs baseline: 1.1827x; 1.1827x over previous
//
#include <hip/hip_runtime.h>
#include <hip/hip_fp16.h>

#define N_NODES 100000
#define N_EDGES 1600000
#define NEG_SLOPE 0.2f
#define LN_EPS 1e-5f
#define NB 782            // ceil(N_NODES / 128) buckets, bucket = dst >> 7
#define GEMM_BLOCKS 782   // ceil(N_NODES / 128)
#define BIN_BLOCKS 196    // ceil(N_EDGES / 8192)
#define BIN_EDGES 8192
#define BUCKET_CAP 4096   // padded per-bucket capacity (mean 2048, sigma 45 -> safe)
#define CSR_CAP 2816      // LDS stage capacity per bucket (global fallback above)

typedef _Float16 f16x8 __attribute__((ext_vector_type(8)));
typedef float f32x4 __attribute__((ext_vector_type(4)));

#define XLDS_LD 136       // fp16 row stride for x_lds (128 + 8 pad -> bank spread)

// ---------------- fused MFMA-GEMM + direct-bin mega-kernel (R9, unchanged) -----
__global__ __launch_bounds__(256) void gemm_bin_kernel(const float* __restrict__ x,
                                                       const float* __restrict__ W,
                                                       const float* __restrict__ att_src,
                                                       const float* __restrict__ att_dst,
                                                       const int* __restrict__ ei,
                                                       __half* __restrict__ h16,
                                                       __half* __restrict__ a_srcp,
                                                       float* __restrict__ a_dstp,
                                                       int* __restrict__ bucket_cursor,
                                                       unsigned* __restrict__ binned) {
    // union LDS: GEMM uses x_lds (34,816 B) + w_frag (32,768 B); bin uses 2 int arrays
    __shared__ __align__(16) char lds[34816 + 32768];
    const int t = threadIdx.x;

    if (blockIdx.x >= GEMM_BLOCKS) {
        // ---------------- direct-bin branch ----------------
        int* hist = reinterpret_cast<int*>(lds);
        int* cbase = reinterpret_cast<int*>(lds + 4096);
        for (int i = t; i < NB; i += 256) hist[i] = 0;
        __syncthreads();
        const int e0 = (blockIdx.x - GEMM_BLOCKS) * BIN_EDGES;
        const int4* dsts = reinterpret_cast<const int4*>(ei + N_EDGES);
        const int b4 = e0 >> 2;
        for (int i = t; i < BIN_EDGES / 4; i += 256) {
            int idx = b4 + i;
            if (idx < N_EDGES / 4) {
                int4 d = dsts[idx];
                atomicAdd(&hist[d.x >> 7], 1);
                atomicAdd(&hist[d.y >> 7], 1);
                atomicAdd(&hist[d.z >> 7], 1);
                atomicAdd(&hist[d.w >> 7], 1);
            }
        }
        __syncthreads();
        for (int i = t; i < NB; i += 256) {
            int c = hist[i];
            cbase[i] = c ? atomicAdd(&bucket_cursor[i], c) : 0;
        }
        __syncthreads();
        for (int i = t; i < NB; i += 256) hist[i] = 0;   // reuse as local cursor
        __syncthreads();
        for (int i = t; i < BIN_EDGES; i += 256) {
            int e = e0 + i;
            if (e < N_EDGES) {
                int s_ = ei[e];
                int d = ei[N_EDGES + e];
                int bk = d >> 7;
                int off = atomicAdd(&hist[bk], 1);
                binned[bk * BUCKET_CAP + cbase[bk] + off] = (unsigned)((s_ << 7) | (d & 127));
            }
        }
        return;
    }

    // ---------------- MFMA GEMM branch ----------------
    _Float16* x_lds = reinterpret_cast<_Float16*>(lds);            // [128][XLDS_LD]
    _Float16* w_frag = reinterpret_cast<_Float16*>(lds + 34816);   // [4][8][64][8]
    const int nbase = blockIdx.x * 128;
    const int w = t >> 6;      // wave 0..3
    const int l = t & 63;
    const int lr = l & 15;     // A-row / B-col / D-col within tile
    const int lg = l >> 4;     // 16-lane group 0..3

    // stage x tile fp32 -> fp16 (coalesced float4 reads, 16B LDS writes)
    for (int i = t; i < 2048; i += 256) {
        int r = i >> 4, seg = i & 15;
        int gr = nbase + r;
        gr = gr < N_NODES ? gr : N_NODES - 1;
        const float4 v0 = *reinterpret_cast<const float4*>(&x[(size_t)gr * 128 + seg * 8]);
        const float4 v1 = *reinterpret_cast<const float4*>(&x[(size_t)gr * 128 + seg * 8 + 4]);
        _Float16 hb[8] = {(_Float16)v0.x, (_Float16)v0.y, (_Float16)v0.z, (_Float16)v0.w,
                          (_Float16)v1.x, (_Float16)v1.y, (_Float16)v1.z, (_Float16)v1.w};
        *reinterpret_cast<uint4*>(&x_lds[r * XLDS_LD + seg * 8]) =
            *reinterpret_cast<const uint4*>(hb);
    }
    // stage W into B-fragment order: w_frag[((ks*8+ct)*64+lane)*8 + j]
    //   = W[ks*32 + (lane>>4)*8 + j][ct*16 + (lane&15)]   (L2-hot strided reads)
    for (int s = t; s < 2048; s += 256) {
        int ks = s >> 9, ct = (s >> 6) & 7, ln = s & 63;
        int kb = ks * 32 + (ln >> 4) * 8;
        int col = ct * 16 + (ln & 15);
        _Float16 wb[8];
#pragma unroll
        for (int j = 0; j < 8; ++j) wb[j] = (_Float16)W[(size_t)(kb + j) * 128 + col];
        *reinterpret_cast<uint4*>(&w_frag[s * 8]) = *reinterpret_cast<const uint4*>(wb);
    }
    __syncthreads();

    f32x4 acc[2][8] = {};
    const int m0 = w * 32;
#pragma unroll
    for (int ks = 0; ks < 4; ++ks) {
        f16x8 a[2], b[8];
#pragma unroll
        for (int rt = 0; rt < 2; ++rt)
            a[rt] = *reinterpret_cast<const f16x8*>(
                &x_lds[(m0 + rt * 16 + lr) * XLDS_LD + ks * 32 + lg * 8]);
#pragma unroll
        for (int ct = 0; ct < 8; ++ct)
            b[ct] = *reinterpret_cast<const f16x8*>(&w_frag[((ks * 8 + ct) * 64 + l) * 8]);
#pragma unroll
        for (int rt = 0; rt < 2; ++rt)
#pragma unroll
            for (int ct = 0; ct < 8; ++ct)
                acc[rt][ct] = __builtin_amdgcn_mfma_f32_16x16x32_f16(a[rt], b[ct],
                                                                     acc[rt][ct], 0, 0, 0);
    }
    __syncthreads();   // done reading x_lds/w_frag; reuse x_lds for h output
    // D mapping (m89-verified): D[(lane>>4)*4 + reg][lane&15] per 16x16 tile
#pragma unroll
    for (int rt = 0; rt < 2; ++rt)
#pragma unroll
        for (int ct = 0; ct < 8; ++ct)
#pragma unroll
            for (int reg = 0; reg < 4; ++reg)
                x_lds[(m0 + rt * 16 + lg * 4 + reg) * XLDS_LD + ct * 16 + lr] =
                    (_Float16)acc[rt][ct][reg];
    __syncthreads();
    // coalesced h16 store
    for (int i = t; i < 2048; i += 256) {
        int r = i >> 4, seg = i & 15;
        int gr = nbase + r;
        if (gr < N_NODES)
            *reinterpret_cast<uint4*>(&h16[(size_t)gr * 128 + seg * 8]) =
                *reinterpret_cast<const uint4*>(&x_lds[r * XLDS_LD + seg * 8]);
    }
    // a_src / a_dst epilogue from the LDS h copy
    for (int idx = t; idx < 1024; idx += 256) {
        int row = idx >> 3, hd = idx & 7;
        int gr = nbase + row;
        if (gr < N_NODES) {
            float ps = 0.f, pd = 0.f;
#pragma unroll
            for (int j = 0; j < 16; ++j) {
                const float hv = (float)x_lds[row * XLDS_LD + hd * 16 + j];
                ps = fmaf(hv, att_src[hd * 16 + j], ps);
                pd = fmaf(hv, att_dst[hd * 16 + j], pd);
            }
            a_srcp[gr * 8 + hd] = __float2half_rn(ps);
            a_dstp[gr * 8 + hd] = pd;
        }
    }
}

// ---------------- build row_beg/row_end + csr_src (padded), one block/bucket ----
__global__ __launch_bounds__(256) void csr_build_kernel(const unsigned* __restrict__ binned,
                                                        const int* __restrict__ bucket_cursor,
                                                        int* __restrict__ row_beg,
                                                        int* __restrict__ row_end,
                                                        int* __restrict__ csr_src) {
    __shared__ int deg[128];
    __shared__ int sc[128];
    __shared__ int cur[128];
    __shared__ unsigned stage[CSR_CAP];
    const int b = blockIdx.x;
    const int t = threadIdx.x;
    const int pbase = b * BUCKET_CAP;
    const int cnt = bucket_cursor[b];
    const int n0 = b << 7;
    const bool fits = cnt <= CSR_CAP;
    if (t < 128) deg[t] = 0;
    __syncthreads();
    if (fits) {
        for (int i = t; i < cnt; i += 256) {
            unsigned p = binned[pbase + i];
            stage[i] = p;
            atomicAdd(&deg[p & 127], 1);
        }
    } else {
        for (int i = t; i < cnt; i += 256)
            atomicAdd(&deg[binned[pbase + i] & 127], 1);
    }
    __syncthreads();
    if (t < 128) sc[t] = deg[t];
    __syncthreads();
    for (int off = 1; off < 128; off <<= 1) {
        int u = (t < 128 && t >= off) ? sc[t - off] : 0;
        __syncthreads();
        if (t < 128) sc[t] += u;
        __syncthreads();
    }
    if (t < 128) {
        int excl = sc[t] - deg[t];
        cur[t] = excl;
        int n = n0 + t;
        if (n < N_NODES) {
            row_beg[n] = pbase + excl;
            row_end[n] = pbase + excl + deg[t];
        }
    }
    __syncthreads();
    if (fits) {
        for (int i = t; i < cnt; i += 256) {
            unsigned p = stage[i];
            int off = atomicAdd(&cur[p & 127], 1);
            csr_src[pbase + off] = (int)(p >> 7);
        }
    } else {
        for (int i = t; i < cnt; i += 256) {
            unsigned p = binned[pbase + i];
            int off = atomicAdd(&cur[p & 127], 1);
            csr_src[pbase + off] = (int)(p >> 7);
        }
    }
}

// ---------------- fused per-node aggregate + softmax + LN ----------------
// one 64-lane wave per node, four 16-lane quarters; quarter q owns edges
// beg+q, beg+q+4, ...  R5-proven depth-2 loop (best measured 83.2-83.8 µs):
// single prefetch slot, index fetched 2 iterations ahead, gather 1 ahead;
// tail prefetches clamp to the row's own first edge (hot line, zero HBM cost).
// lane-within-quarter ql owns channels 8*ql..8*ql+7 (one uint4 of fp16).
// h16 row stride = 128 * 2 B = 256 B.
__global__ __launch_bounds__(256) void node_aggregate_kernel(const int* __restrict__ row_beg,
                                                             const int* __restrict__ row_end,
                                                             const int* __restrict__ csr_src,
                                                             const __half* __restrict__ h16,
                                                             const __half* __restrict__ a_srcp,
                                                             const float* __restrict__ a_dstp,
                                                             const float* __restrict__ x,
                                                             const float* __restrict__ bias,
                                                             const float* __restrict__ gamma,
                                                             const float* __restrict__ beta,
                                                             float* __restrict__ out) {
    int node = blockIdx.x * 4 + (threadIdx.x >> 6);
    if (node >= N_NODES) return;
    const int lane = threadIdx.x & 63;
    const int q = lane >> 4;           // quarter 0..3
    const int ql = lane & 15;          // lane within quarter
    const int ch = ql * 8;             // 8 channels per lane
    const int head = ql >> 1;          // 2 lanes per head

    const float adst = a_dstp[node * 8 + head];

    const int beg = row_beg[node];
    const int end = row_end[node];

    float s = 0.f;
    float accv[8] = {};

    const char* __restrict__ hbase = reinterpret_cast<const char*>(h16);
    const unsigned chb = (unsigned)(ql * 16);   // byte offset of this lane's chunk

#define LOADH(dst_, sidx_) \
    dst_ = *reinterpret_cast<const uint4*>(hbase + ((unsigned)(sidx_) * 256u + chb))
#define LOADA(dst_, sidx_) dst_ = __half2float(a_srcp[(sidx_) * 8 + head])

    int i = beg + q;
    if (i < end) {
        const int sF = csr_src[i];
        int s1 = (i + 4 < end) ? csr_src[i + 4] : sF;
        uint4 hv;
        float as;
        LOADH(hv, sF);
        LOADA(as, sF);
        while (true) {
            const uint4 hc = hv;
            const float ac = as;
            const int sN = s1;
            const int i8 = i + 8;
            s1 = (i8 < end) ? csr_src[i8] : sF;      // index 2 iterations ahead
            LOADH(hv, sN);                            // gather 1 iteration ahead
            LOADA(as, sN);

            float e = ac + adst;
            e = fmaxf(e, NEG_SLOPE * e);
            e = fminf(e, 80.f);
            const float p = __expf(e);
            s += p;
            const __half* hh = reinterpret_cast<const __half*>(&hc);
#pragma unroll
            for (int j = 0; j < 8; ++j)
                accv[j] = fmaf(p, __half2float(hh[j]), accv[j]);

            i += 4;
            if (i >= end) break;
        }
    }
#undef LOADH
#undef LOADA

    // combine the four quarters (each channel present in all quarters)
    s += __shfl_xor(s, 16);
    s += __shfl_xor(s, 32);
#pragma unroll
    for (int j = 0; j < 8; ++j) {
        accv[j] += __shfl_xor(accv[j], 16);
        accv[j] += __shfl_xor(accv[j], 32);
    }

    // normalize + bias + residual (x is touch-once: non-temporal)
    const float rs = 1.0f / (s + 1e-16f);
    const float* xrp = x + (size_t)node * 128 + ch;
    float v[8];
#pragma unroll
    for (int j = 0; j < 8; ++j) {
        const float xr = __builtin_nontemporal_load(xrp + j);
        v[j] = accv[j] * rs + bias[ch + j] + xr;
    }

    // LayerNorm: quarters identical after combine -> reduce over 16 lanes, /128
    float sum = 0.f, sq = 0.f;
#pragma unroll
    for (int j = 0; j < 8; ++j) {
        sum += v[j];
        sq = fmaf(v[j], v[j], sq);
    }
#pragma unroll
    for (int off = 8; off > 0; off >>= 1) {
        sum += __shfl_xor(sum, off);
        sq += __shfl_xor(sq, off);
    }
    const float mu = sum * (1.0f / 128.0f);
    const float var = sq * (1.0f / 128.0f) - mu * mu;
    const float inv = rsqrtf(var + LN_EPS);
    if (q == 0) {
        float o[8];
#pragma unroll
        for (int j = 0; j < 8; ++j) {
            float tt = (v[j] - mu) * inv * gamma[ch + j] + beta[ch + j];
            o[j] = tt > 0.f ? tt : 0.f;
        }
        float* op = out + (size_t)node * 128 + ch;
#pragma unroll
        for (int j = 0; j < 8; ++j) __builtin_nontemporal_store(o[j], op + j);
    }
}

extern "C" void kernel_launch(void* const* d_in, const int* in_sizes, int n_in,
                              void* d_out, int out_size, void* d_ws, size_t ws_size,
                              hipStream_t stream) {
    const float* x = (const float*)d_in[0];
    const int* ei = (const int*)d_in[1];
    const float* W = (const float*)d_in[2];
    const float* att_src = (const float*)d_in[3];
    const float* att_dst = (const float*)d_in[4];
    const float* bias = (const float*)d_in[5];
    const float* gamma = (const float*)d_in[6];
    const float* beta = (const float*)d_in[7];
    float* out = (float*)d_out;

    char* base = (char*)d_ws;
    __half* h16    = (__half*)base;                     // 25.6 MB
    __half* a_srcp = (__half*)(base + 25600000);        // 1.6 MB
    float* a_dstp  = (float*)(base + 27200000);         // 3.2 MB
    int* csr_src   = (int*)(base + 30400000);           // 12.81 MB (padded 782*4096*4)
    int* row_beg   = (int*)(base + 43212288);           // 400 KB
    int* row_end   = (int*)(base + 43612288);           // 400 KB
    unsigned* binned = (unsigned*)(base + 44012288);    // 12.81 MB (padded)
    int* bucket_cursor = (int*)(base + 56824576);       // 3,128 B

    hipMemsetAsync(bucket_cursor, 0, NB * sizeof(int), stream);
    gemm_bin_kernel<<<GEMM_BLOCKS + BIN_BLOCKS, 256, 0, stream>>>(
        x, W, att_src, att_dst, ei, h16, a_srcp, a_dstp, bucket_cursor, binned);
    csr_build_kernel<<<NB, 256, 0, stream>>>(binned, bucket_cursor, row_beg, row_end, csr_src);
    node_aggregate_kernel<<<(N_NODES + 3) / 4, 256, 0, stream>>>(
        row_beg, row_end, csr_src, h16, a_srcp, a_dstp, x, bias, gamma, beta, out);
}

// Round 13
// 145.384 us; speedup vs baseline: 1.1996x; 1.0143x over previous
//
#include <hip/hip_runtime.h>
#include <hip/hip_fp16.h>

#define N_NODES 100000
#define N_EDGES 1600000
#define NEG_SLOPE 0.2f
#define LN_EPS 1e-5f
#define NB 782            // ceil(N_NODES / 128) buckets, bucket = dst >> 7
#define GEMM_BLOCKS 782   // ceil(N_NODES / 128)
#define BIN_BLOCKS 196    // ceil(N_EDGES / 8192)
#define BIN_EDGES 8192
#define BUCKET_CAP 4096   // padded per-bucket capacity (mean 2048, sigma 45 -> safe)
#define CSR_CAP 2816      // LDS stage capacity per bucket (global fallback above)

typedef _Float16 f16x8 __attribute__((ext_vector_type(8)));
typedef float f32x4 __attribute__((ext_vector_type(4)));

#define XLDS_LD 136       // fp16 row stride for x_lds (128 + 8 pad -> bank spread)

// ---------------- fused MFMA-GEMM + direct-bin mega-kernel -----
// blocks [0, GEMM_BLOCKS): h16 = fp16(x @ W) via v_mfma_f32_16x16x32_f16,
//   fused a_src(fp16)/a_dst(fp32) epilogue; ALSO stores x16 = fp16(x) from the
//   staged LDS tile (saves the aggregate 25.6 MB of fp32 residual stream).
// blocks [GEMM_BLOCKS, +BIN_BLOCKS): two-pass LDS bin of edges into PADDED
//   per-bucket regions binned[bucket*BUCKET_CAP + ...].
__global__ __launch_bounds__(256) void gemm_bin_kernel(const float* __restrict__ x,
                                                       const float* __restrict__ W,
                                                       const float* __restrict__ att_src,
                                                       const float* __restrict__ att_dst,
                                                       const int* __restrict__ ei,
                                                       __half* __restrict__ h16,
                                                       __half* __restrict__ x16,
                                                       __half* __restrict__ a_srcp,
                                                       float* __restrict__ a_dstp,
                                                       int* __restrict__ bucket_cursor,
                                                       unsigned* __restrict__ binned) {
    // union LDS: GEMM uses x_lds (34,816 B) + w_frag (32,768 B); bin uses 2 int arrays
    __shared__ __align__(16) char lds[34816 + 32768];
    const int t = threadIdx.x;

    if (blockIdx.x >= GEMM_BLOCKS) {
        // ---------------- direct-bin branch ----------------
        int* hist = reinterpret_cast<int*>(lds);
        int* cbase = reinterpret_cast<int*>(lds + 4096);
        for (int i = t; i < NB; i += 256) hist[i] = 0;
        __syncthreads();
        const int e0 = (blockIdx.x - GEMM_BLOCKS) * BIN_EDGES;
        const int4* dsts = reinterpret_cast<const int4*>(ei + N_EDGES);
        const int b4 = e0 >> 2;
        for (int i = t; i < BIN_EDGES / 4; i += 256) {
            int idx = b4 + i;
            if (idx < N_EDGES / 4) {
                int4 d = dsts[idx];
                atomicAdd(&hist[d.x >> 7], 1);
                atomicAdd(&hist[d.y >> 7], 1);
                atomicAdd(&hist[d.z >> 7], 1);
                atomicAdd(&hist[d.w >> 7], 1);
            }
        }
        __syncthreads();
        for (int i = t; i < NB; i += 256) {
            int c = hist[i];
            cbase[i] = c ? atomicAdd(&bucket_cursor[i], c) : 0;
        }
        __syncthreads();
        for (int i = t; i < NB; i += 256) hist[i] = 0;   // reuse as local cursor
        __syncthreads();
        for (int i = t; i < BIN_EDGES; i += 256) {
            int e = e0 + i;
            if (e < N_EDGES) {
                int s_ = ei[e];
                int d = ei[N_EDGES + e];
                int bk = d >> 7;
                int off = atomicAdd(&hist[bk], 1);
                binned[bk * BUCKET_CAP + cbase[bk] + off] = (unsigned)((s_ << 7) | (d & 127));
            }
        }
        return;
    }

    // ---------------- MFMA GEMM branch ----------------
    _Float16* x_lds = reinterpret_cast<_Float16*>(lds);            // [128][XLDS_LD]
    _Float16* w_frag = reinterpret_cast<_Float16*>(lds + 34816);   // [4][8][64][8]
    const int nbase = blockIdx.x * 128;
    const int w = t >> 6;      // wave 0..3
    const int l = t & 63;
    const int lr = l & 15;     // A-row / B-col / D-col within tile
    const int lg = l >> 4;     // 16-lane group 0..3

    // stage x tile fp32 -> fp16 (coalesced float4 reads, 16B LDS writes)
    for (int i = t; i < 2048; i += 256) {
        int r = i >> 4, seg = i & 15;
        int gr = nbase + r;
        gr = gr < N_NODES ? gr : N_NODES - 1;
        const float4 v0 = *reinterpret_cast<const float4*>(&x[(size_t)gr * 128 + seg * 8]);
        const float4 v1 = *reinterpret_cast<const float4*>(&x[(size_t)gr * 128 + seg * 8 + 4]);
        _Float16 hb[8] = {(_Float16)v0.x, (_Float16)v0.y, (_Float16)v0.z, (_Float16)v0.w,
                          (_Float16)v1.x, (_Float16)v1.y, (_Float16)v1.z, (_Float16)v1.w};
        *reinterpret_cast<uint4*>(&x_lds[r * XLDS_LD + seg * 8]) =
            *reinterpret_cast<const uint4*>(hb);
    }
    // stage W into B-fragment order: w_frag[((ks*8+ct)*64+lane)*8 + j]
    //   = W[ks*32 + (lane>>4)*8 + j][ct*16 + (lane&15)]   (L2-hot strided reads)
    for (int s = t; s < 2048; s += 256) {
        int ks = s >> 9, ct = (s >> 6) & 7, ln = s & 63;
        int kb = ks * 32 + (ln >> 4) * 8;
        int col = ct * 16 + (ln & 15);
        _Float16 wb[8];
#pragma unroll
        for (int j = 0; j < 8; ++j) wb[j] = (_Float16)W[(size_t)(kb + j) * 128 + col];
        *reinterpret_cast<uint4*>(&w_frag[s * 8]) = *reinterpret_cast<const uint4*>(wb);
    }
    __syncthreads();

    // x16 store: fp16 copy of the staged x tile (reads x_lds; no hazard until the
    // D-write barrier below)
    for (int i = t; i < 2048; i += 256) {
        int r = i >> 4, seg = i & 15;
        int gr = nbase + r;
        if (gr < N_NODES)
            *reinterpret_cast<uint4*>(&x16[(size_t)gr * 128 + seg * 8]) =
                *reinterpret_cast<const uint4*>(&x_lds[r * XLDS_LD + seg * 8]);
    }

    f32x4 acc[2][8] = {};
    const int m0 = w * 32;
#pragma unroll
    for (int ks = 0; ks < 4; ++ks) {
        f16x8 a[2], b[8];
#pragma unroll
        for (int rt = 0; rt < 2; ++rt)
            a[rt] = *reinterpret_cast<const f16x8*>(
                &x_lds[(m0 + rt * 16 + lr) * XLDS_LD + ks * 32 + lg * 8]);
#pragma unroll
        for (int ct = 0; ct < 8; ++ct)
            b[ct] = *reinterpret_cast<const f16x8*>(&w_frag[((ks * 8 + ct) * 64 + l) * 8]);
#pragma unroll
        for (int rt = 0; rt < 2; ++rt)
#pragma unroll
            for (int ct = 0; ct < 8; ++ct)
                acc[rt][ct] = __builtin_amdgcn_mfma_f32_16x16x32_f16(a[rt], b[ct],
                                                                     acc[rt][ct], 0, 0, 0);
    }
    __syncthreads();   // done reading x_lds/w_frag; reuse x_lds for h output
    // D mapping (m89-verified): D[(lane>>4)*4 + reg][lane&15] per 16x16 tile
#pragma unroll
    for (int rt = 0; rt < 2; ++rt)
#pragma unroll
        for (int ct = 0; ct < 8; ++ct)
#pragma unroll
            for (int reg = 0; reg < 4; ++reg)
                x_lds[(m0 + rt * 16 + lg * 4 + reg) * XLDS_LD + ct * 16 + lr] =
                    (_Float16)acc[rt][ct][reg];
    __syncthreads();
    // coalesced h16 store
    for (int i = t; i < 2048; i += 256) {
        int r = i >> 4, seg = i & 15;
        int gr = nbase + r;
        if (gr < N_NODES)
            *reinterpret_cast<uint4*>(&h16[(size_t)gr * 128 + seg * 8]) =
                *reinterpret_cast<const uint4*>(&x_lds[r * XLDS_LD + seg * 8]);
    }
    // a_src / a_dst epilogue from the LDS h copy
    for (int idx = t; idx < 1024; idx += 256) {
        int row = idx >> 3, hd = idx & 7;
        int gr = nbase + row;
        if (gr < N_NODES) {
            float ps = 0.f, pd = 0.f;
#pragma unroll
            for (int j = 0; j < 16; ++j) {
                const float hv = (float)x_lds[row * XLDS_LD + hd * 16 + j];
                ps = fmaf(hv, att_src[hd * 16 + j], ps);
                pd = fmaf(hv, att_dst[hd * 16 + j], pd);
            }
            a_srcp[gr * 8 + hd] = __float2half_rn(ps);
            a_dstp[gr * 8 + hd] = pd;
        }
    }
}

// ---------------- build row_beg/row_end + csr_src (padded), one block/bucket ----
__global__ __launch_bounds__(256) void csr_build_kernel(const unsigned* __restrict__ binned,
                                                        const int* __restrict__ bucket_cursor,
                                                        int* __restrict__ row_beg,
                                                        int* __restrict__ row_end,
                                                        int* __restrict__ csr_src) {
    __shared__ int deg[128];
    __shared__ int sc[128];
    __shared__ int cur[128];
    __shared__ unsigned stage[CSR_CAP];
    const int b = blockIdx.x;
    const int t = threadIdx.x;
    const int pbase = b * BUCKET_CAP;
    const int cnt = bucket_cursor[b];
    const int n0 = b << 7;
    const bool fits = cnt <= CSR_CAP;
    if (t < 128) deg[t] = 0;
    __syncthreads();
    if (fits) {
        for (int i = t; i < cnt; i += 256) {
            unsigned p = binned[pbase + i];
            stage[i] = p;
            atomicAdd(&deg[p & 127], 1);
        }
    } else {
        for (int i = t; i < cnt; i += 256)
            atomicAdd(&deg[binned[pbase + i] & 127], 1);
    }
    __syncthreads();
    if (t < 128) sc[t] = deg[t];
    __syncthreads();
    for (int off = 1; off < 128; off <<= 1) {
        int u = (t < 128 && t >= off) ? sc[t - off] : 0;
        __syncthreads();
        if (t < 128) sc[t] += u;
        __syncthreads();
    }
    if (t < 128) {
        int excl = sc[t] - deg[t];
        cur[t] = excl;
        int n = n0 + t;
        if (n < N_NODES) {
            row_beg[n] = pbase + excl;
            row_end[n] = pbase + excl + deg[t];
        }
    }
    __syncthreads();
    if (fits) {
        for (int i = t; i < cnt; i += 256) {
            unsigned p = stage[i];
            int off = atomicAdd(&cur[p & 127], 1);
            csr_src[pbase + off] = (int)(p >> 7);
        }
    } else {
        for (int i = t; i < cnt; i += 256) {
            unsigned p = binned[pbase + i];
            int off = atomicAdd(&cur[p & 127], 1);
            csr_src[pbase + off] = (int)(p >> 7);
        }
    }
}

// ---------------- fused per-node aggregate + softmax + LN ----------------
// one 64-lane wave per node, four 16-lane quarters; R5-proven depth-2 loop.
// Residual read from x16 (fp16) — 25.6 MB instead of 51.2 MB fp32.
// h16 row stride = 128 * 2 B = 256 B.
__global__ __launch_bounds__(256) void node_aggregate_kernel(const int* __restrict__ row_beg,
                                                             const int* __restrict__ row_end,
                                                             const int* __restrict__ csr_src,
                                                             const __half* __restrict__ h16,
                                                             const __half* __restrict__ a_srcp,
                                                             const float* __restrict__ a_dstp,
                                                             const __half* __restrict__ x16,
                                                             const float* __restrict__ bias,
                                                             const float* __restrict__ gamma,
                                                             const float* __restrict__ beta,
                                                             float* __restrict__ out) {
    int node = blockIdx.x * 4 + (threadIdx.x >> 6);
    if (node >= N_NODES) return;
    const int lane = threadIdx.x & 63;
    const int q = lane >> 4;           // quarter 0..3
    const int ql = lane & 15;          // lane within quarter
    const int ch = ql * 8;             // 8 channels per lane
    const int head = ql >> 1;          // 2 lanes per head

    const float adst = a_dstp[node * 8 + head];

    const int beg = row_beg[node];
    const int end = row_end[node];

    float s = 0.f;
    float accv[8] = {};

    const char* __restrict__ hbase = reinterpret_cast<const char*>(h16);
    const unsigned chb = (unsigned)(ql * 16);   // byte offset of this lane's chunk

#define LOADH(dst_, sidx_) \
    dst_ = *reinterpret_cast<const uint4*>(hbase + ((unsigned)(sidx_) * 256u + chb))
#define LOADA(dst_, sidx_) dst_ = __half2float(a_srcp[(sidx_) * 8 + head])

    int i = beg + q;
    if (i < end) {
        const int sF = csr_src[i];
        int s1 = (i + 4 < end) ? csr_src[i + 4] : sF;
        uint4 hv;
        float as;
        LOADH(hv, sF);
        LOADA(as, sF);
        while (true) {
            const uint4 hc = hv;
            const float ac = as;
            const int sN = s1;
            const int i8 = i + 8;
            s1 = (i8 < end) ? csr_src[i8] : sF;      // index 2 iterations ahead
            LOADH(hv, sN);                            // gather 1 iteration ahead
            LOADA(as, sN);

            float e = ac + adst;
            e = fmaxf(e, NEG_SLOPE * e);
            e = fminf(e, 80.f);
            const float p = __expf(e);
            s += p;
            const __half* hh = reinterpret_cast<const __half*>(&hc);
#pragma unroll
            for (int j = 0; j < 8; ++j)
                accv[j] = fmaf(p, __half2float(hh[j]), accv[j]);

            i += 4;
            if (i >= end) break;
        }
    }
#undef LOADH
#undef LOADA

    // combine the four quarters (each channel present in all quarters)
    s += __shfl_xor(s, 16);
    s += __shfl_xor(s, 32);
#pragma unroll
    for (int j = 0; j < 8; ++j) {
        accv[j] += __shfl_xor(accv[j], 16);
        accv[j] += __shfl_xor(accv[j], 32);
    }

    // normalize + bias + residual (x16 fp16, touch-once: non-temporal 8B loads)
    const float rs = 1.0f / (s + 1e-16f);
    const unsigned long long* xrp =
        reinterpret_cast<const unsigned long long*>(x16 + (size_t)node * 128 + ch);
    unsigned long long xw0 = __builtin_nontemporal_load(xrp);
    unsigned long long xw1 = __builtin_nontemporal_load(xrp + 1);
    __half xr[8];
    *reinterpret_cast<unsigned long long*>(&xr[0]) = xw0;
    *reinterpret_cast<unsigned long long*>(&xr[4]) = xw1;
    float v[8];
#pragma unroll
    for (int j = 0; j < 8; ++j)
        v[j] = accv[j] * rs + bias[ch + j] + __half2float(xr[j]);

    // LayerNorm: quarters identical after combine -> reduce over 16 lanes, /128
    float sum = 0.f, sq = 0.f;
#pragma unroll
    for (int j = 0; j < 8; ++j) {
        sum += v[j];
        sq = fmaf(v[j], v[j], sq);
    }
#pragma unroll
    for (int off = 8; off > 0; off >>= 1) {
        sum += __shfl_xor(sum, off);
        sq += __shfl_xor(sq, off);
    }
    const float mu = sum * (1.0f / 128.0f);
    const float var = sq * (1.0f / 128.0f) - mu * mu;
    const float inv = rsqrtf(var + LN_EPS);
    if (q == 0) {
        float o[8];
#pragma unroll
        for (int j = 0; j < 8; ++j) {
            float tt = (v[j] - mu) * inv * gamma[ch + j] + beta[ch + j];
            o[j] = tt > 0.f ? tt : 0.f;
        }
        float* op = out + (size_t)node * 128 + ch;
#pragma unroll
        for (int j = 0; j < 8; ++j) __builtin_nontemporal_store(o[j], op + j);
    }
}

extern "C" void kernel_launch(void* const* d_in, const int* in_sizes, int n_in,
                              void* d_out, int out_size, void* d_ws, size_t ws_size,
                              hipStream_t stream) {
    const float* x = (const float*)d_in[0];
    const int* ei = (const int*)d_in[1];
    const float* W = (const float*)d_in[2];
    const float* att_src = (const float*)d_in[3];
    const float* att_dst = (const float*)d_in[4];
    const float* bias = (const float*)d_in[5];
    const float* gamma = (const float*)d_in[6];
    const float* beta = (const float*)d_in[7];
    float* out = (float*)d_out;

    char* base = (char*)d_ws;
    __half* h16    = (__half*)base;                     // 25.6 MB
    __half* a_srcp = (__half*)(base + 25600000);        // 1.6 MB
    float* a_dstp  = (float*)(base + 27200000);         // 3.2 MB
    int* csr_src   = (int*)(base + 30400000);           // 12.81 MB (padded 782*4096*4)
    int* row_beg   = (int*)(base + 43212288);           // 400 KB
    int* row_end   = (int*)(base + 43612288);           // 400 KB
    unsigned* binned = (unsigned*)(base + 44012288);    // 12.81 MB (padded)
    int* bucket_cursor = (int*)(base + 56824576);       // 3,128 B
    __half* x16    = (__half*)(base + 56827904);        // 25.6 MB

    hipMemsetAsync(bucket_cursor, 0, NB * sizeof(int), stream);
    gemm_bin_kernel<<<GEMM_BLOCKS + BIN_BLOCKS, 256, 0, stream>>>(
        x, W, att_src, att_dst, ei, h16, x16, a_srcp, a_dstp, bucket_cursor, binned);
    csr_build_kernel<<<NB, 256, 0, stream>>>(binned, bucket_cursor, row_beg, row_end, csr_src);
    node_aggregate_kernel<<<(N_NODES + 3) / 4, 256, 0, stream>>>(
        row_beg, row_end, csr_src, h16, a_srcp, a_dstp, x16, bias, gamma, beta, out);
}